// Round 1
// baseline (49.436 us; speedup 1.0000x reference)
//
#include <hip/hip_runtime.h>
#include <hip/hip_bf16.h>

// Problem: B=16, C=256, H=64, W=64, OUT=256
//   scale[b,c] = mean(context[b,c,:,:])
//   out[b,o,hw] = sum_c w1[o,c]*scale[b,c]*x[b,c,hw] + b1[o]
// Strategy: fold scale into w1 -> per-batch bf16 GEMM via MFMA (memory-bound).

typedef __attribute__((ext_vector_type(8))) short short8;
typedef __attribute__((ext_vector_type(4))) float f32x4;

static __device__ __forceinline__ unsigned short f2bf(float f) {
    unsigned int u = __float_as_uint(f);
    unsigned int r = u + 0x7FFFu + ((u >> 16) & 1u);  // round-to-nearest-even
    return (unsigned short)(r >> 16);
}

// ---------------- Kernel 1: scale[b*256+c] = mean over 4096 elems ----------
__global__ __launch_bounds__(256) void scale_kernel(const float* __restrict__ ctx,
                                                    float* __restrict__ scale) {
    const int bc = blockIdx.x;              // 0..4095
    const float4* p = (const float4*)(ctx + (size_t)bc * 4096);
    const int t = threadIdx.x;
    float s = 0.f;
#pragma unroll
    for (int k = 0; k < 4; k++) {
        float4 v = p[t + k * 256];
        s += v.x + v.y + v.z + v.w;
    }
#pragma unroll
    for (int off = 32; off > 0; off >>= 1) s += __shfl_down(s, off);
    __shared__ float ws[4];
    if ((t & 63) == 0) ws[t >> 6] = s;
    __syncthreads();
    if (t == 0) scale[bc] = (ws[0] + ws[1] + ws[2] + ws[3]) * (1.0f / 4096.0f);
}

// ---------------- Kernel 2: w2[b][o][c] = bf16(w1[o][c] * scale[b][c]) -----
__global__ __launch_bounds__(256) void w2_kernel(const float* __restrict__ w1,
                                                 const float* __restrict__ scale,
                                                 unsigned short* __restrict__ w2) {
    const int idx = blockIdx.x * 256 + threadIdx.x;  // 0..262143 (each does 4 elems)
    const int c4 = idx * 4;                          // flat index into [16][256][256]
    const int b = c4 >> 16;
    const int oc = c4 & 65535;                       // o*256 + c
    const int c = oc & 255;
    float4 w = *(const float4*)(w1 + oc);
    float4 sc = *(const float4*)(scale + b * 256 + c);
    ushort4 r;
    r.x = f2bf(w.x * sc.x);
    r.y = f2bf(w.y * sc.y);
    r.z = f2bf(w.z * sc.z);
    r.w = f2bf(w.w * sc.w);
    *(ushort4*)(w2 + (size_t)b * 65536 + oc) = r;
}

// ---------------- Kernel 3: per-batch GEMM out = w2[b] (256x256) * x[b] (256x4096) + b1
// Block: 256 threads = 4 waves. BM=256 (full M), BN=64. Wave w owns rows [64w,64w+64).
// No LDS: A-frags direct from L2-resident w2; B-frags per-lane f32 loads from x, cvt to bf16.
__global__ __launch_bounds__(256) void gemm_kernel(const float* __restrict__ x,
                                                   const unsigned short* __restrict__ w2,
                                                   const float* __restrict__ b1,
                                                   float* __restrict__ out) {
    const int bid = blockIdx.x;      // 1024 blocks
    const int b = bid >> 6;          // batch
    const int hw0 = (bid & 63) * 64; // column tile
    const int w = threadIdx.x >> 6;
    const int lane = threadIdx.x & 63;
    const int g = lane >> 4;         // 0..3
    const int lr = lane & 15;        // 0..15
    const int o0 = w * 64;

    const unsigned short* Aw = w2 + (size_t)b * 65536;     // [256][256] bf16
    const float* Xb = x + (size_t)b * (256 * 4096);        // [256][4096] f32

    f32x4 acc[4][4];
#pragma unroll
    for (int m = 0; m < 4; m++)
#pragma unroll
        for (int n = 0; n < 4; n++) acc[m][n] = (f32x4)(0.f);

    // per-lane base for B loads: + e*4096 walks k within the 8-elem group
    const float* xcol = Xb + (size_t)(g * 8) * 4096 + hw0 + lr;

#pragma unroll
    for (int ks = 0; ks < 8; ks++) {
        short8 a[4];
#pragma unroll
        for (int m = 0; m < 4; m++)
            a[m] = *(const short8*)(Aw + (o0 + m * 16 + lr) * 256 + ks * 32 + g * 8);
#pragma unroll
        for (int n = 0; n < 4; n++) {
            const float* p = xcol + (size_t)ks * 32 * 4096 + n * 16;
            short8 bf;
#pragma unroll
            for (int e = 0; e < 8; e++) bf[e] = (short)f2bf(p[(size_t)e * 4096]);
#pragma unroll
            for (int m = 0; m < 4; m++)
                acc[m][n] = __builtin_amdgcn_mfma_f32_16x16x32_bf16(a[m], bf, acc[m][n], 0, 0, 0);
        }
    }

    // Epilogue: D col = lane&15, row = 4*(lane>>4)+reg (m89-verified layout)
    float* outb = out + ((size_t)b * 256) * 4096;
#pragma unroll
    for (int m = 0; m < 4; m++) {
        float bias[4];
#pragma unroll
        for (int r = 0; r < 4; r++) bias[r] = b1[o0 + m * 16 + g * 4 + r];
#pragma unroll
        for (int n = 0; n < 4; n++) {
#pragma unroll
            for (int r = 0; r < 4; r++) {
                const int row = o0 + m * 16 + g * 4 + r;
                outb[(size_t)row * 4096 + hw0 + n * 16 + lr] = acc[m][n][r] + bias[r];
            }
        }
    }
}

extern "C" void kernel_launch(void* const* d_in, const int* in_sizes, int n_in,
                              void* d_out, int out_size, void* d_ws, size_t ws_size,
                              hipStream_t stream) {
    const float* x = (const float*)d_in[0];       // [16,256,64,64]
    const float* context = (const float*)d_in[1]; // [16,256,64,64]
    const float* w1 = (const float*)d_in[2];      // [256,256]
    const float* b1 = (const float*)d_in[3];      // [256]
    float* out = (float*)d_out;

    // workspace: scale (4096 f32 = 16KB) | w2 (16*256*256 bf16 = 2MB)
    float* scale = (float*)d_ws;
    unsigned short* w2 = (unsigned short*)((char*)d_ws + 16384);

    scale_kernel<<<4096, 256, 0, stream>>>(context, scale);
    w2_kernel<<<1024, 256, 0, stream>>>(w1, scale, w2);
    gemm_kernel<<<1024, 256, 0, stream>>>(x, w2, b1, out);
}